// Round 25
// baseline (508.720 us; speedup 1.0000x reference)
//
#include <hip/hip_runtime.h>
#include <hip/hip_bf16.h>
#include <math.h>
#include <stdint.h>

#define TOK 32768
#define DIM 1024
#define NE 8
#define NSEG 16                      /* (k, expert) segments */
#define BMCAP (2 * TOK + NSEG * 256) /* 69632 row slots (segments padded to 256) */

#define C_CNT(s) ((s) * 16)
#define C_CUR(s) (256 + (s) * 16)
#define C_SEG(s) (512 + (s))

typedef __attribute__((ext_vector_type(8))) short bf16x8;
typedef __attribute__((ext_vector_type(4))) float f32x4;
typedef __attribute__((ext_vector_type(4))) unsigned short u16x4;
typedef unsigned short ushort_t;

__device__ __forceinline__ unsigned short f2b(float x) {
  union { float f; unsigned u; } v; v.f = x;
  unsigned r = v.u + 0x7fffu + ((v.u >> 16) & 1u);
  return (unsigned short)(r >> 16);
}

__device__ __forceinline__ float b2f(unsigned short u) {
  union { unsigned u; float f; } v;
  v.u = ((unsigned)u) << 16;
  return v.f;
}

// fast gelu: logistic form of tanh-approx; |err vs erf-gelu| <= ~3e-4
__device__ __forceinline__ float gelu_fast(float x) {
  const float y2 = -1.5957691216057308f * x * fmaf(0.044715f, x * x, 1.0f);
  return x * __builtin_amdgcn_rcpf(1.0f + __expf(y2));
}

__device__ __forceinline__ void async16(void* lds, const void* g) {
  auto* lp = (__attribute__((address_space(3))) uint32_t*)lds;
  auto* gp = (__attribute__((address_space(1))) uint32_t*)(const_cast<void*>(g));
  __builtin_amdgcn_global_load_lds(gp, lp, 16, 0, 0);
}

// ---- router v4: FROZEN sequential fmaf chain + fused X16 cast --------------
__global__ __launch_bounds__(256) void router_seq3(
    const float* __restrict__ tokens, const float* __restrict__ rw,
    int* __restrict__ topi, float* __restrict__ topv,
    ushort_t* __restrict__ x16) {
  __shared__ float xs[2][32][132];
  __shared__ float wsh[2][8][132];
  __shared__ float sc[256];
  const int tid = threadIdx.x;
  const int e = tid & 7;
  const int tr = tid >> 3;
  const int t0 = blockIdx.x * 32;

  float4 lx0, lx1, lx2, lx3, lw;
  auto issue = [&](int c) {
    const int col = (tid & 31) * 4;
    lx0 = *(const float4*)&tokens[(size_t)(t0 + ((tid + 0) >> 5)) * DIM + c * 128 + col];
    lx1 = *(const float4*)&tokens[(size_t)(t0 + ((tid + 256) >> 5)) * DIM + c * 128 + col];
    lx2 = *(const float4*)&tokens[(size_t)(t0 + ((tid + 512) >> 5)) * DIM + c * 128 + col];
    lx3 = *(const float4*)&tokens[(size_t)(t0 + ((tid + 768) >> 5)) * DIM + c * 128 + col];
    lw  = *(const float4*)&rw[(size_t)(tid >> 5) * DIM + c * 128 + col];
  };
  auto commit = [&](int b) {
    const int col = (tid & 31) * 4;
    *(float4*)&xs[b][(tid + 0) >> 5][col] = lx0;
    *(float4*)&xs[b][(tid + 256) >> 5][col] = lx1;
    *(float4*)&xs[b][(tid + 512) >> 5][col] = lx2;
    *(float4*)&xs[b][(tid + 768) >> 5][col] = lx3;
    *(float4*)&wsh[b][tid >> 5][col] = lw;
  };
  auto commitX = [&](int c) { // fused tokens->bf16 (same RNE as cast_tokens)
    const int col = c * 128 + (tid & 31) * 4;
    u16x4 u;
    u[0] = f2b(lx0.x); u[1] = f2b(lx0.y); u[2] = f2b(lx0.z); u[3] = f2b(lx0.w);
    *(u16x4*)&x16[(size_t)(t0 + ((tid + 0) >> 5)) * DIM + col] = u;
    u[0] = f2b(lx1.x); u[1] = f2b(lx1.y); u[2] = f2b(lx1.z); u[3] = f2b(lx1.w);
    *(u16x4*)&x16[(size_t)(t0 + ((tid + 256) >> 5)) * DIM + col] = u;
    u[0] = f2b(lx2.x); u[1] = f2b(lx2.y); u[2] = f2b(lx2.z); u[3] = f2b(lx2.w);
    *(u16x4*)&x16[(size_t)(t0 + ((tid + 512) >> 5)) * DIM + col] = u;
    u[0] = f2b(lx3.x); u[1] = f2b(lx3.y); u[2] = f2b(lx3.z); u[3] = f2b(lx3.w);
    *(u16x4*)&x16[(size_t)(t0 + ((tid + 768) >> 5)) * DIM + col] = u;
  };

  issue(0);
  commit(0);
  commitX(0);
  __syncthreads();
  float s = 0.f;
  for (int c = 0; c < 8; c++) {
    const int b = c & 1;
    if (c + 1 < 8) issue(c + 1);
#pragma unroll
    for (int k4 = 0; k4 < 32; k4++) {
      const float4 xv = *(const float4*)&xs[b][tr][k4 * 4];
      const float4 wv = *(const float4*)&wsh[b][e][k4 * 4];
      s = fmaf(xv.x, wv.x, s);
      s = fmaf(xv.y, wv.y, s);
      s = fmaf(xv.z, wv.z, s);
      s = fmaf(xv.w, wv.w, s);
    }
    if (c + 1 < 8) {
      commit(b ^ 1);
      commitX(c + 1);
    }
    __syncthreads();
  }
  sc[tid] = s;
  __syncthreads();
  if (e == 0) {
    float p[NE];
    float m = sc[tr * 8];
#pragma unroll
    for (int i = 1; i < NE; i++) m = fmaxf(m, sc[tr * 8 + i]);
    float sum = 0.f;
#pragma unroll
    for (int i = 0; i < NE; i++) {
      p[i] = expf(sc[tr * 8 + i] - m);
      sum += p[i];
    }
#pragma unroll
    for (int i = 0; i < NE; i++) p[i] = p[i] / sum;
    const int t = t0 + tr;
    int e0 = 0;
#pragma unroll
    for (int i = 1; i < NE; i++) if (p[i] > p[e0]) e0 = i;
    int e1 = (e0 == 0) ? 1 : 0;
#pragma unroll
    for (int i = 0; i < NE; i++) if (i != e0 && p[i] > p[e1]) e1 = i;
    topi[t * 2] = e0;     topv[t * 2] = p[e0];
    topi[t * 2 + 1] = e1; topv[t * 2 + 1] = p[e1];
  }
}

// ---- per-(k,expert) counts -------------------------------------------------
__global__ __launch_bounds__(256) void hist_kernel(const int* __restrict__ topi,
                                                   int* __restrict__ ctrl) {
  __shared__ int h[NSEG];
  const int tid = threadIdx.x;
  if (tid < NSEG) h[tid] = 0;
  __syncthreads();
  const int t = blockIdx.x * 256 + tid;
  atomicAdd(&h[topi[t * 2]], 1);
  atomicAdd(&h[8 + topi[t * 2 + 1]], 1);
  __syncthreads();
  if (tid < NSEG) atomicAdd(&ctrl[C_CNT(tid)], h[tid]);
}

__global__ void prefix_kernel(int* ctrl) {
  if (threadIdx.x == 0 && blockIdx.x == 0) {
    int s = 0;
    for (int g = 0; g < NSEG; g++) {
      ctrl[C_SEG(g)] = s;
      ctrl[C_CUR(g)] = s;
      s += (ctrl[C_CNT(g)] + 255) & ~255; /* pad segments to 256 (BM) */
    }
    ctrl[C_SEG(NSEG)] = s;
  }
}

__global__ __launch_bounds__(256) void init_rows(int* __restrict__ row_token) {
  const int i = blockIdx.x * 256 + threadIdx.x;
  if (i < BMCAP) row_token[i] = TOK;
}

// ---- assign: slot scatter + inverse map (token -> slot) --------------------
__global__ __launch_bounds__(256) void assign2(
    const int* __restrict__ topi, int* __restrict__ ctrl,
    int* __restrict__ row_token, int* __restrict__ inv) {
  __shared__ int h[NSEG];
  __shared__ int base[NSEG];
  const int tid = threadIdx.x;
  const int t = blockIdx.x * 256 + tid;
  if (tid < NSEG) h[tid] = 0;
  __syncthreads();
  const int s0 = topi[t * 2], s1 = 8 + topi[t * 2 + 1];
  const int o0 = atomicAdd(&h[s0], 1);
  const int o1 = atomicAdd(&h[s1], 1);
  __syncthreads();
  if (tid < NSEG) base[tid] = atomicAdd(&ctrl[C_CUR(tid)], h[tid]);
  __syncthreads();
  const int p0 = base[s0] + o0, p1 = base[s1] + o1;
  row_token[p0] = t; inv[t * 2] = p0;
  row_token[p1] = t; inv[t * 2 + 1] = p1;
}

// ---- weights: both w1,w2 [E][K][N] f32 -> [E][N][K] bf16 in ONE dispatch ---
__global__ __launch_bounds__(256) void transpose_cast2(
    const float* __restrict__ w1, const float* __restrict__ w2,
    ushort_t* __restrict__ w1T, ushort_t* __restrict__ w2T) {
  __shared__ float tile[64][65];
  const int z = blockIdx.z;
  const int e = z & 7;
  const float* src = (z < 8 ? w1 : w2) + ((size_t)e << 20);
  ushort_t* dst = (z < 8 ? w1T : w2T) + ((size_t)e << 20);
  const int n0 = blockIdx.x * 64, k0 = blockIdx.y * 64;
  const int tx = threadIdx.x & 63, ty = threadIdx.x >> 6;
#pragma unroll
  for (int r = ty; r < 64; r += 4)
    tile[r][tx] = src[(size_t)(k0 + r) * DIM + n0 + tx];
  __syncthreads();
#pragma unroll
  for (int r = ty; r < 64; r += 4)
    dst[(size_t)(n0 + r) * DIM + k0 + tx] = f2b(tile[tx][r]);
}

// ---- combine: out[t] = gY[slot0] + gY[slot1]  (gate pre-applied) -----------
__global__ __launch_bounds__(256) void combine(
    const ushort_t* __restrict__ gY, const int* __restrict__ inv,
    float* __restrict__ out) {
  const size_t i = (size_t)blockIdx.x * 256 + threadIdx.x;
  const int t = (int)(i >> 7);
  const int c = (int)(i & 127) << 3;
  const int s0 = inv[t * 2], s1 = inv[t * 2 + 1];
  const bf16x8 y0 = *(const bf16x8*)&gY[(size_t)s0 * DIM + c];
  const bf16x8 y1 = *(const bf16x8*)&gY[(size_t)s1 * DIM + c];
  f32x4 o0, o1;
#pragma unroll
  for (int j = 0; j < 4; j++)
    o0[j] = b2f((unsigned short)y0[j]) + b2f((unsigned short)y1[j]);
#pragma unroll
  for (int j = 0; j < 4; j++)
    o1[j] = b2f((unsigned short)y0[4 + j]) + b2f((unsigned short)y1[4 + j]);
  float* op = out + (size_t)t * DIM + c;
  *(f32x4*)op = o0;
  *(f32x4*)(op + 4) = o1;
}

// --- grouped GEMM: 256x128 tile, BK=32, 8 waves, dbuf, 2 blocks/CU ----------
// r22/r24-VERIFIED shape (202us, VGPR 56, MfmaUtil 31%). Structural optimum:
// LDS pipe ~67% busy at inherent b128 width; reuse capped by VGPR (r23/r20).
// launch_bounds(512,4): do NOT raise (r20: (512,6) spilled acc, 3.2x slow).
// PASS 0: H[rr,:]  = gelu(X16[row_token[rr],:] @ w1T[e]^T)         (bf16)
// PASS 1: gY[rr,:] = g(rr) * ( H[rr,:] @ w2T[e]^T )   g = topv[tok*2+k]
template <int PASS>
__global__ __launch_bounds__(512, 4) void dgemm(
    const ushort_t* __restrict__ Asrc, const ushort_t* __restrict__ Wt,
    const int* __restrict__ row_token, const float* __restrict__ topv,
    const int* __restrict__ ctrl, int chunk, ushort_t* __restrict__ Hout) {
  const int l = (blockIdx.x & 7) * chunk + (blockIdx.x >> 3);
  const int mt = l >> 3, nt = l & 7; // n-fastest: 8 blocks share an A-panel
  const int rend = ctrl[C_SEG(NSEG)];
  const int m0 = mt * 256;
  if (m0 >= rend) return;
  const int n0 = nt * 128;
  int sg = 0;
  for (int i = 1; i < NSEG; i++)
    if (m0 >= ctrl[C_SEG(i)]) sg = i;
  const int e = sg & 7;
  const int kk = sg >> 3; // top-k index of this segment
  const ushort_t* B = Wt + ((size_t)e << 20);

  __shared__ __align__(16) char smem[49152];
  ushort_t (*As)[8192] = (ushort_t(*)[8192])smem;           // 2 x 16 KB
  ushort_t (*Bs)[4096] = (ushort_t(*)[4096])(smem + 32768); // 2 x 8 KB
  float* scratch = (float*)smem; // epilogue: 64x128 f32 = 32 KB

  const int tid = threadIdx.x;
  const int lane = tid & 63;
  const int wave = tid >> 6;
  const int wm = wave >> 1, wn = wave & 1; // per-wave 64x64 output
  const int lr = lane & 15;
  const int kx = (((lane >> 4) ^ (lr & 3) ^ ((lr >> 2) & 3)) << 3);

  const int ko = (((lane & 3) ^ ((lane >> 2) & 3) ^ ((lane >> 4) & 3)) << 3);
  const int ar0 = wave * 32 + (lane >> 2);
  const int brr = wave * 16 + (lane >> 2);
  const ushort_t *asrc0, *asrc1, *bsrc;
  if (PASS == 0) {
    int tk0 = row_token[m0 + ar0];
    int tk1 = row_token[m0 + ar0 + 16];
    if (tk0 >= TOK) tk0 = 0;
    if (tk1 >= TOK) tk1 = 0;
    asrc0 = Asrc + (size_t)tk0 * DIM + ko;
    asrc1 = Asrc + (size_t)tk1 * DIM + ko;
  } else {
    asrc0 = Asrc + (size_t)(m0 + ar0) * DIM + ko;
    asrc1 = Asrc + (size_t)(m0 + ar0 + 16) * DIM + ko;
  }
  bsrc = B + (size_t)(n0 + brr) * DIM + ko;

  f32x4 acc[4][4] = {};

  auto stage = [&](int b, int k0) {
    async16(&As[b][wave * 1024], asrc0 + k0);
    async16(&As[b][wave * 1024 + 512], asrc1 + k0);
    async16(&Bs[b][wave * 512], bsrc + k0);
  };
  auto compute = [&](int b) {
    bf16x8 a[4], bb[4];
#pragma unroll
    for (int mi = 0; mi < 4; mi++)
      a[mi] = *(const bf16x8*)&As[b][(wm * 64 + mi * 16 + lr) * 32 + kx];
#pragma unroll
    for (int ni = 0; ni < 4; ni++)
      bb[ni] = *(const bf16x8*)&Bs[b][(wn * 64 + ni * 16 + lr) * 32 + kx];
#pragma unroll
    for (int mi = 0; mi < 4; mi++)
#pragma unroll
      for (int ni = 0; ni < 4; ni++)
        acc[mi][ni] = __builtin_amdgcn_mfma_f32_16x16x32_bf16(
            a[mi], bb[ni], acc[mi][ni], 0, 0, 0);
  };

  stage(0, 0);
  __syncthreads();
  int cur = 0;
#pragma unroll 1
  for (int t = 0; t < 31; t++) {
    stage(cur ^ 1, (t + 1) * 32);
    compute(cur);
    __syncthreads();
    cur ^= 1;
  }
  compute(cur);
  __syncthreads(); // K-loop done; smem becomes scratch

  // ---- epilogue: 4 rounds (one 64-row m-block each), coalesced stores -----
  const int grow = (lane >> 4) << 2;
  const int erow = tid >> 3;       // 0..63
  const int ec0 = (tid & 7) * 16;  // col base, 16 cols/thread
#pragma unroll 1
  for (int rnd = 0; rnd < 4; rnd++) {
    if (wm == rnd) {
#pragma unroll
      for (int mi = 0; mi < 4; mi++) {
#pragma unroll
        for (int ni = 0; ni < 4; ni++) {
#pragma unroll
          for (int r = 0; r < 4; r++) {
            const int lrow = mi * 16 + grow + r;
            const int lcol = (wn * 64 + ni * 16 + lr) ^ ((lrow & 3) << 2);
            scratch[lrow * 128 + lcol] = acc[mi][ni][r];
          }
        }
      }
    }
    __syncthreads();
    {
      const int q = (erow & 3) << 2;
      f32x4 v[4];
#pragma unroll
      for (int k = 0; k < 4; k++)
        v[k] = *(const f32x4*)&scratch[erow * 128 + ((ec0 + 4 * k) ^ q)];
      const int rr = m0 + rnd * 64 + erow;
      bf16x8 h0, h1;
      if (PASS == 0) {
#pragma unroll
        for (int k = 0; k < 2; k++)
#pragma unroll
          for (int j = 0; j < 4; j++)
            h0[k * 4 + j] = (short)f2b(gelu_fast(v[k][j]));
#pragma unroll
        for (int k = 0; k < 2; k++)
#pragma unroll
          for (int j = 0; j < 4; j++)
            h1[k * 4 + j] = (short)f2b(gelu_fast(v[2 + k][j]));
      } else {
        const int tok = row_token[rr];
        const float g = (tok < TOK) ? topv[tok * 2 + kk] : 0.f;
#pragma unroll
        for (int k = 0; k < 2; k++)
#pragma unroll
          for (int j = 0; j < 4; j++) h0[k * 4 + j] = (short)f2b(g * v[k][j]);
#pragma unroll
        for (int k = 0; k < 2; k++)
#pragma unroll
          for (int j = 0; j < 4; j++)
            h1[k * 4 + j] = (short)f2b(g * v[2 + k][j]);
      }
      *(bf16x8*)&Hout[(size_t)rr * DIM + n0 + ec0] = h0;
      *(bf16x8*)&Hout[(size_t)rr * DIM + n0 + ec0 + 8] = h1;
    }
    __syncthreads();
  }
}

extern "C" void kernel_launch(void* const* d_in, const int* in_sizes, int n_in,
                              void* d_out, int out_size, void* d_ws,
                              size_t ws_size, hipStream_t stream) {
  (void)in_sizes; (void)n_in; (void)ws_size; (void)out_size;
  const float* tokens = (const float*)d_in[0];
  const float* rw = (const float*)d_in[1];
  const float* w1 = (const float*)d_in[2];
  const float* w2 = (const float*)d_in[3];
  float* out = (float*)d_out;

  char* ws = (char*)d_ws;
  size_t off = 0;
  auto alloc = [&](size_t b) {
    size_t o = off;
    off += (b + 255) & ~(size_t)255;
    return o;
  };
  int* ctrl = (int*)(ws + alloc(4096));
  int* topi = (int*)(ws + alloc((size_t)TOK * 2 * 4));
  float* topv = (float*)(ws + alloc((size_t)TOK * 2 * 4));
  int* inv = (int*)(ws + alloc((size_t)TOK * 2 * 4));
  int* row_token = (int*)(ws + alloc((size_t)BMCAP * 4));
  ushort_t* w2T = (ushort_t*)(ws + alloc((size_t)NE * DIM * DIM * 2));
  ushort_t* H = (ushort_t*)(ws + alloc((size_t)BMCAP * DIM * 2));
  // region: X16 + w1T (pass-0 only) overlaid by gY (pass-1 output)
  const size_t region = alloc((size_t)BMCAP * DIM * 2); // 142.6 MB
  ushort_t* X16 = (ushort_t*)(ws + region);                         // 67 MB
  ushort_t* w1T = (ushort_t*)(ws + region + (size_t)TOK * DIM * 2); // 16.8 MB
  ushort_t* gY = (ushort_t*)(ws + region); // aliases X16+w1T (dead by pass-1)

  hipMemsetAsync(ctrl, 0, 4096, stream);
  router_seq3<<<TOK / 32, 256, 0, stream>>>(tokens, rw, topi, topv, X16);
  hist_kernel<<<TOK / 256, 256, 0, stream>>>(topi, ctrl);
  prefix_kernel<<<1, 64, 0, stream>>>(ctrl);
  init_rows<<<BMCAP / 256, 256, 0, stream>>>(row_token);
  assign2<<<TOK / 256, 256, 0, stream>>>(topi, ctrl, row_token, inv);
  dim3 tg(16, 16, 16);
  transpose_cast2<<<tg, 256, 0, stream>>>(w1, w2, w1T, w2T);
  // pass-0: all 16 segments -> H (272 m-tiles x 8 n-tiles = 2176 blocks)
  dgemm<0><<<2176, 512, 0, stream>>>(X16, w1T, row_token, topv, ctrl, 272, H);
  // pass-1: all 16 segments -> gY (gate pre-applied, coalesced)
  dgemm<1><<<2176, 512, 0, stream>>>(H, w2T, row_token, topv, ctrl, 272, gY);
  // combine: out[t] = gY[slot0] + gY[slot1]
  combine<<<TOK * (DIM / 8) / 256, 256, 0, stream>>>(gY, inv, out);
}

// Round 26
// 495.105 us; speedup vs baseline: 1.0275x; 1.0275x over previous
//
#include <hip/hip_runtime.h>
#include <hip/hip_bf16.h>
#include <math.h>
#include <stdint.h>

#define TOK 32768
#define DIM 1024
#define NE 8
#define NSEG 16                      /* (k, expert) segments */
#define BMCAP (2 * TOK + NSEG * 256) /* 69632 row slots (segments padded to 256) */

#define C_CNT(s) ((s) * 16)
#define C_CUR(s) (256 + (s) * 16)
#define C_SEG(s) (512 + (s))

typedef __attribute__((ext_vector_type(8))) short bf16x8;
typedef __attribute__((ext_vector_type(4))) float f32x4;
typedef __attribute__((ext_vector_type(4))) unsigned short u16x4;
typedef unsigned short ushort_t;

#define VMCNT(n) asm volatile("s_waitcnt vmcnt(" #n ")" ::: "memory")
__device__ __forceinline__ void barrier_raw() {
  __builtin_amdgcn_sched_barrier(0);
  __builtin_amdgcn_s_barrier();
  __builtin_amdgcn_sched_barrier(0);
}

__device__ __forceinline__ unsigned short f2b(float x) {
  union { float f; unsigned u; } v; v.f = x;
  unsigned r = v.u + 0x7fffu + ((v.u >> 16) & 1u);
  return (unsigned short)(r >> 16);
}

__device__ __forceinline__ float b2f(unsigned short u) {
  union { unsigned u; float f; } v;
  v.u = ((unsigned)u) << 16;
  return v.f;
}

// fast gelu: logistic form of tanh-approx; |err vs erf-gelu| <= ~3e-4
__device__ __forceinline__ float gelu_fast(float x) {
  const float y2 = -1.5957691216057308f * x * fmaf(0.044715f, x * x, 1.0f);
  return x * __builtin_amdgcn_rcpf(1.0f + __expf(y2));
}

__device__ __forceinline__ void async16(void* lds, const void* g) {
  auto* lp = (__attribute__((address_space(3))) uint32_t*)lds;
  auto* gp = (__attribute__((address_space(1))) uint32_t*)(const_cast<void*>(g));
  __builtin_amdgcn_global_load_lds(gp, lp, 16, 0, 0);
}

// ---- router v4: FROZEN sequential fmaf chain + fused X16 cast --------------
__global__ __launch_bounds__(256) void router_seq3(
    const float* __restrict__ tokens, const float* __restrict__ rw,
    int* __restrict__ topi, float* __restrict__ topv,
    ushort_t* __restrict__ x16) {
  __shared__ float xs[2][32][132];
  __shared__ float wsh[2][8][132];
  __shared__ float sc[256];
  const int tid = threadIdx.x;
  const int e = tid & 7;
  const int tr = tid >> 3;
  const int t0 = blockIdx.x * 32;

  float4 lx0, lx1, lx2, lx3, lw;
  auto issue = [&](int c) {
    const int col = (tid & 31) * 4;
    lx0 = *(const float4*)&tokens[(size_t)(t0 + ((tid + 0) >> 5)) * DIM + c * 128 + col];
    lx1 = *(const float4*)&tokens[(size_t)(t0 + ((tid + 256) >> 5)) * DIM + c * 128 + col];
    lx2 = *(const float4*)&tokens[(size_t)(t0 + ((tid + 512) >> 5)) * DIM + c * 128 + col];
    lx3 = *(const float4*)&tokens[(size_t)(t0 + ((tid + 768) >> 5)) * DIM + c * 128 + col];
    lw  = *(const float4*)&rw[(size_t)(tid >> 5) * DIM + c * 128 + col];
  };
  auto commit = [&](int b) {
    const int col = (tid & 31) * 4;
    *(float4*)&xs[b][(tid + 0) >> 5][col] = lx0;
    *(float4*)&xs[b][(tid + 256) >> 5][col] = lx1;
    *(float4*)&xs[b][(tid + 512) >> 5][col] = lx2;
    *(float4*)&xs[b][(tid + 768) >> 5][col] = lx3;
    *(float4*)&wsh[b][tid >> 5][col] = lw;
  };
  auto commitX = [&](int c) { // fused tokens->bf16 (same RNE as cast_tokens)
    const int col = c * 128 + (tid & 31) * 4;
    u16x4 u;
    u[0] = f2b(lx0.x); u[1] = f2b(lx0.y); u[2] = f2b(lx0.z); u[3] = f2b(lx0.w);
    *(u16x4*)&x16[(size_t)(t0 + ((tid + 0) >> 5)) * DIM + col] = u;
    u[0] = f2b(lx1.x); u[1] = f2b(lx1.y); u[2] = f2b(lx1.z); u[3] = f2b(lx1.w);
    *(u16x4*)&x16[(size_t)(t0 + ((tid + 256) >> 5)) * DIM + col] = u;
    u[0] = f2b(lx2.x); u[1] = f2b(lx2.y); u[2] = f2b(lx2.z); u[3] = f2b(lx2.w);
    *(u16x4*)&x16[(size_t)(t0 + ((tid + 512) >> 5)) * DIM + col] = u;
    u[0] = f2b(lx3.x); u[1] = f2b(lx3.y); u[2] = f2b(lx3.z); u[3] = f2b(lx3.w);
    *(u16x4*)&x16[(size_t)(t0 + ((tid + 768) >> 5)) * DIM + col] = u;
  };

  issue(0);
  commit(0);
  commitX(0);
  __syncthreads();
  float s = 0.f;
  for (int c = 0; c < 8; c++) {
    const int b = c & 1;
    if (c + 1 < 8) issue(c + 1);
#pragma unroll
    for (int k4 = 0; k4 < 32; k4++) {
      const float4 xv = *(const float4*)&xs[b][tr][k4 * 4];
      const float4 wv = *(const float4*)&wsh[b][e][k4 * 4];
      s = fmaf(xv.x, wv.x, s);
      s = fmaf(xv.y, wv.y, s);
      s = fmaf(xv.z, wv.z, s);
      s = fmaf(xv.w, wv.w, s);
    }
    if (c + 1 < 8) {
      commit(b ^ 1);
      commitX(c + 1);
    }
    __syncthreads();
  }
  sc[tid] = s;
  __syncthreads();
  if (e == 0) {
    float p[NE];
    float m = sc[tr * 8];
#pragma unroll
    for (int i = 1; i < NE; i++) m = fmaxf(m, sc[tr * 8 + i]);
    float sum = 0.f;
#pragma unroll
    for (int i = 0; i < NE; i++) {
      p[i] = expf(sc[tr * 8 + i] - m);
      sum += p[i];
    }
#pragma unroll
    for (int i = 0; i < NE; i++) p[i] = p[i] / sum;
    const int t = t0 + tr;
    int e0 = 0;
#pragma unroll
    for (int i = 1; i < NE; i++) if (p[i] > p[e0]) e0 = i;
    int e1 = (e0 == 0) ? 1 : 0;
#pragma unroll
    for (int i = 0; i < NE; i++) if (i != e0 && p[i] > p[e1]) e1 = i;
    topi[t * 2] = e0;     topv[t * 2] = p[e0];
    topi[t * 2 + 1] = e1; topv[t * 2 + 1] = p[e1];
  }
}

// ---- per-(k,expert) counts -------------------------------------------------
__global__ __launch_bounds__(256) void hist_kernel(const int* __restrict__ topi,
                                                   int* __restrict__ ctrl) {
  __shared__ int h[NSEG];
  const int tid = threadIdx.x;
  if (tid < NSEG) h[tid] = 0;
  __syncthreads();
  const int t = blockIdx.x * 256 + tid;
  atomicAdd(&h[topi[t * 2]], 1);
  atomicAdd(&h[8 + topi[t * 2 + 1]], 1);
  __syncthreads();
  if (tid < NSEG) atomicAdd(&ctrl[C_CNT(tid)], h[tid]);
}

__global__ void prefix_kernel(int* ctrl) {
  if (threadIdx.x == 0 && blockIdx.x == 0) {
    int s = 0;
    for (int g = 0; g < NSEG; g++) {
      ctrl[C_SEG(g)] = s;
      ctrl[C_CUR(g)] = s;
      s += (ctrl[C_CNT(g)] + 255) & ~255; /* pad segments to 256 (BM) */
    }
    ctrl[C_SEG(NSEG)] = s;
  }
}

__global__ __launch_bounds__(256) void init_rows(int* __restrict__ row_token) {
  const int i = blockIdx.x * 256 + threadIdx.x;
  if (i < BMCAP) row_token[i] = TOK;
}

// ---- assign: slot scatter + inverse map (token -> slot) --------------------
__global__ __launch_bounds__(256) void assign2(
    const int* __restrict__ topi, int* __restrict__ ctrl,
    int* __restrict__ row_token, int* __restrict__ inv) {
  __shared__ int h[NSEG];
  __shared__ int base[NSEG];
  const int tid = threadIdx.x;
  const int t = blockIdx.x * 256 + tid;
  if (tid < NSEG) h[tid] = 0;
  __syncthreads();
  const int s0 = topi[t * 2], s1 = 8 + topi[t * 2 + 1];
  const int o0 = atomicAdd(&h[s0], 1);
  const int o1 = atomicAdd(&h[s1], 1);
  __syncthreads();
  if (tid < NSEG) base[tid] = atomicAdd(&ctrl[C_CUR(tid)], h[tid]);
  __syncthreads();
  const int p0 = base[s0] + o0, p1 = base[s1] + o1;
  row_token[p0] = t; inv[t * 2] = p0;
  row_token[p1] = t; inv[t * 2 + 1] = p1;
}

// ---- weights: both w1,w2 [E][K][N] f32 -> [E][N][K] bf16 in ONE dispatch ---
__global__ __launch_bounds__(256) void transpose_cast2(
    const float* __restrict__ w1, const float* __restrict__ w2,
    ushort_t* __restrict__ w1T, ushort_t* __restrict__ w2T) {
  __shared__ float tile[64][65];
  const int z = blockIdx.z;
  const int e = z & 7;
  const float* src = (z < 8 ? w1 : w2) + ((size_t)e << 20);
  ushort_t* dst = (z < 8 ? w1T : w2T) + ((size_t)e << 20);
  const int n0 = blockIdx.x * 64, k0 = blockIdx.y * 64;
  const int tx = threadIdx.x & 63, ty = threadIdx.x >> 6;
#pragma unroll
  for (int r = ty; r < 64; r += 4)
    tile[r][tx] = src[(size_t)(k0 + r) * DIM + n0 + tx];
  __syncthreads();
#pragma unroll
  for (int r = ty; r < 64; r += 4)
    dst[(size_t)(n0 + r) * DIM + k0 + tx] = f2b(tile[tx][r]);
}

// ---- combine: out[t] = gY[slot0] + gY[slot1]  (gate pre-applied) -----------
__global__ __launch_bounds__(256) void combine(
    const ushort_t* __restrict__ gY, const int* __restrict__ inv,
    float* __restrict__ out) {
  const size_t i = (size_t)blockIdx.x * 256 + threadIdx.x;
  const int t = (int)(i >> 7);
  const int c = (int)(i & 127) << 3;
  const int s0 = inv[t * 2], s1 = inv[t * 2 + 1];
  const bf16x8 y0 = *(const bf16x8*)&gY[(size_t)s0 * DIM + c];
  const bf16x8 y1 = *(const bf16x8*)&gY[(size_t)s1 * DIM + c];
  f32x4 o0, o1;
#pragma unroll
  for (int j = 0; j < 4; j++)
    o0[j] = b2f((unsigned short)y0[j]) + b2f((unsigned short)y1[j]);
#pragma unroll
  for (int j = 0; j < 4; j++)
    o1[j] = b2f((unsigned short)y0[4 + j]) + b2f((unsigned short)y1[4 + j]);
  float* op = out + (size_t)t * DIM + c;
  *(f32x4*)op = o0;
  *(f32x4*)(op + 4) = o1;
}

// --- grouped GEMM: 256x128, BK=32, 8 waves, 3-BUF RING + counted vmcnt ------
// NEW vs r25: stage 2 tiles ahead; per K-iter:
//   stage(t+2) -> vmcnt(6) -> s_barrier -> compute(t) -> s_barrier
// vmcnt(6): 3 loads/thread/tile, 9 outstanding at gate, wait oldest 3 (tile t)
// — loads stay in flight ACROSS barriers (T4); the r16/r17 nulls were at
// 1 block/CU; here LDS ring = 72KB -> 2 blocks/CU keep r19's concurrency.
// launch_bounds(512,4): do NOT raise (r20: (512,6) spilled acc, 3.2x slow).
template <int PASS>
__global__ __launch_bounds__(512, 4) void dgemm(
    const ushort_t* __restrict__ Asrc, const ushort_t* __restrict__ Wt,
    const int* __restrict__ row_token, const float* __restrict__ topv,
    const int* __restrict__ ctrl, int chunk, ushort_t* __restrict__ Hout) {
  const int l = (blockIdx.x & 7) * chunk + (blockIdx.x >> 3);
  const int mt = l >> 3, nt = l & 7; // n-fastest: 8 blocks share an A-panel
  const int rend = ctrl[C_SEG(NSEG)];
  const int m0 = mt * 256;
  if (m0 >= rend) return;
  const int n0 = nt * 128;
  int sg = 0;
  for (int i = 1; i < NSEG; i++)
    if (m0 >= ctrl[C_SEG(i)]) sg = i;
  const int e = sg & 7;
  const int kk = sg >> 3; // top-k index of this segment
  const ushort_t* B = Wt + ((size_t)e << 20);

  __shared__ __align__(16) char smem[73728]; // 3x16KB A + 3x8KB B
  ushort_t (*As)[8192] = (ushort_t(*)[8192])smem;
  ushort_t (*Bs)[4096] = (ushort_t(*)[4096])(smem + 49152);
  float* scratch = (float*)smem; // epilogue: 64x128 f32 = 32 KB

  const int tid = threadIdx.x;
  const int lane = tid & 63;
  const int wave = tid >> 6;
  const int wm = wave >> 1, wn = wave & 1; // per-wave 64x64 output
  const int lr = lane & 15;
  const int kx = (((lane >> 4) ^ (lr & 3) ^ ((lr >> 2) & 3)) << 3);

  const int ko = (((lane & 3) ^ ((lane >> 2) & 3) ^ ((lane >> 4) & 3)) << 3);
  const int ar0 = wave * 32 + (lane >> 2);
  const int brr = wave * 16 + (lane >> 2);
  const ushort_t *asrc0, *asrc1, *bsrc;
  if (PASS == 0) {
    int tk0 = row_token[m0 + ar0];
    int tk1 = row_token[m0 + ar0 + 16];
    if (tk0 >= TOK) tk0 = 0;
    if (tk1 >= TOK) tk1 = 0;
    asrc0 = Asrc + (size_t)tk0 * DIM + ko;
    asrc1 = Asrc + (size_t)tk1 * DIM + ko;
  } else {
    asrc0 = Asrc + (size_t)(m0 + ar0) * DIM + ko;
    asrc1 = Asrc + (size_t)(m0 + ar0 + 16) * DIM + ko;
  }
  bsrc = B + (size_t)(n0 + brr) * DIM + ko;

  f32x4 acc[4][4] = {};

  auto stage = [&](int b, int k0) { // 3 loads per thread per tile
    async16(&As[b][wave * 1024], asrc0 + k0);
    async16(&As[b][wave * 1024 + 512], asrc1 + k0);
    async16(&Bs[b][wave * 512], bsrc + k0);
  };
  auto compute = [&](int b) {
    bf16x8 a[4], bb[4];
#pragma unroll
    for (int mi = 0; mi < 4; mi++)
      a[mi] = *(const bf16x8*)&As[b][(wm * 64 + mi * 16 + lr) * 32 + kx];
#pragma unroll
    for (int ni = 0; ni < 4; ni++)
      bb[ni] = *(const bf16x8*)&Bs[b][(wn * 64 + ni * 16 + lr) * 32 + kx];
#pragma unroll
    for (int mi = 0; mi < 4; mi++)
#pragma unroll
      for (int ni = 0; ni < 4; ni++)
        acc[mi][ni] = __builtin_amdgcn_mfma_f32_16x16x32_bf16(
            a[mi], bb[ni], acc[mi][ni], 0, 0, 0);
  };

  stage(0, 0);
  stage(1, 32);
#pragma unroll 1
  for (int t = 0; t < 30; t++) {
    stage((t + 2) % 3, (t + 2) * 32);
    VMCNT(6); // wait tile t's 3 loads; 6 younger stay in flight
    barrier_raw();
    compute(t % 3);
    barrier_raw();
  }
  VMCNT(3);
  barrier_raw();
  compute(0); // tile 30
  barrier_raw();
  VMCNT(0);
  barrier_raw();
  compute(1); // tile 31
  __syncthreads(); // K-loop done; smem becomes scratch

  // ---- epilogue: 4 rounds (one 64-row m-block each), coalesced stores -----
  const int grow = (lane >> 4) << 2;
  const int erow = tid >> 3;       // 0..63
  const int ec0 = (tid & 7) * 16;  // col base, 16 cols/thread
#pragma unroll 1
  for (int rnd = 0; rnd < 4; rnd++) {
    if (wm == rnd) {
#pragma unroll
      for (int mi = 0; mi < 4; mi++) {
#pragma unroll
        for (int ni = 0; ni < 4; ni++) {
#pragma unroll
          for (int r = 0; r < 4; r++) {
            const int lrow = mi * 16 + grow + r;
            const int lcol = (wn * 64 + ni * 16 + lr) ^ ((lrow & 3) << 2);
            scratch[lrow * 128 + lcol] = acc[mi][ni][r];
          }
        }
      }
    }
    __syncthreads();
    {
      const int q = (erow & 3) << 2;
      f32x4 v[4];
#pragma unroll
      for (int k = 0; k < 4; k++)
        v[k] = *(const f32x4*)&scratch[erow * 128 + ((ec0 + 4 * k) ^ q)];
      const int rr = m0 + rnd * 64 + erow;
      bf16x8 h0, h1;
      if (PASS == 0) {
#pragma unroll
        for (int k = 0; k < 2; k++)
#pragma unroll
          for (int j = 0; j < 4; j++)
            h0[k * 4 + j] = (short)f2b(gelu_fast(v[k][j]));
#pragma unroll
        for (int k = 0; k < 2; k++)
#pragma unroll
          for (int j = 0; j < 4; j++)
            h1[k * 4 + j] = (short)f2b(gelu_fast(v[2 + k][j]));
      } else {
        const int tok = row_token[rr];
        const float g = (tok < TOK) ? topv[tok * 2 + kk] : 0.f;
#pragma unroll
        for (int k = 0; k < 2; k++)
#pragma unroll
          for (int j = 0; j < 4; j++) h0[k * 4 + j] = (short)f2b(g * v[k][j]);
#pragma unroll
        for (int k = 0; k < 2; k++)
#pragma unroll
          for (int j = 0; j < 4; j++)
            h1[k * 4 + j] = (short)f2b(g * v[2 + k][j]);
      }
      *(bf16x8*)&Hout[(size_t)rr * DIM + n0 + ec0] = h0;
      *(bf16x8*)&Hout[(size_t)rr * DIM + n0 + ec0 + 8] = h1;
    }
    __syncthreads();
  }
}

extern "C" void kernel_launch(void* const* d_in, const int* in_sizes, int n_in,
                              void* d_out, int out_size, void* d_ws,
                              size_t ws_size, hipStream_t stream) {
  (void)in_sizes; (void)n_in; (void)ws_size; (void)out_size;
  const float* tokens = (const float*)d_in[0];
  const float* rw = (const float*)d_in[1];
  const float* w1 = (const float*)d_in[2];
  const float* w2 = (const float*)d_in[3];
  float* out = (float*)d_out;

  char* ws = (char*)d_ws;
  size_t off = 0;
  auto alloc = [&](size_t b) {
    size_t o = off;
    off += (b + 255) & ~(size_t)255;
    return o;
  };
  int* ctrl = (int*)(ws + alloc(4096));
  int* topi = (int*)(ws + alloc((size_t)TOK * 2 * 4));
  float* topv = (float*)(ws + alloc((size_t)TOK * 2 * 4));
  int* inv = (int*)(ws + alloc((size_t)TOK * 2 * 4));
  int* row_token = (int*)(ws + alloc((size_t)BMCAP * 4));
  ushort_t* w2T = (ushort_t*)(ws + alloc((size_t)NE * DIM * DIM * 2));
  ushort_t* H = (ushort_t*)(ws + alloc((size_t)BMCAP * DIM * 2));
  // region: X16 + w1T (pass-0 only) overlaid by gY (pass-1 output)
  const size_t region = alloc((size_t)BMCAP * DIM * 2); // 142.6 MB
  ushort_t* X16 = (ushort_t*)(ws + region);                         // 67 MB
  ushort_t* w1T = (ushort_t*)(ws + region + (size_t)TOK * DIM * 2); // 16.8 MB
  ushort_t* gY = (ushort_t*)(ws + region); // aliases X16+w1T (dead by pass-1)

  hipMemsetAsync(ctrl, 0, 4096, stream);
  router_seq3<<<TOK / 32, 256, 0, stream>>>(tokens, rw, topi, topv, X16);
  hist_kernel<<<TOK / 256, 256, 0, stream>>>(topi, ctrl);
  prefix_kernel<<<1, 64, 0, stream>>>(ctrl);
  init_rows<<<BMCAP / 256, 256, 0, stream>>>(row_token);
  assign2<<<TOK / 256, 256, 0, stream>>>(topi, ctrl, row_token, inv);
  dim3 tg(16, 16, 16);
  transpose_cast2<<<tg, 256, 0, stream>>>(w1, w2, w1T, w2T);
  // pass-0: all 16 segments -> H (272 m-tiles x 8 n-tiles = 2176 blocks)
  dgemm<0><<<2176, 512, 0, stream>>>(X16, w1T, row_token, topv, ctrl, 272, H);
  // pass-1: all 16 segments -> gY (gate pre-applied, coalesced)
  dgemm<1><<<2176, 512, 0, stream>>>(H, w2T, row_token, topv, ctrl, 272, gY);
  // combine: out[t] = gY[slot0] + gY[slot1]
  combine<<<TOK * (DIM / 8) / 256, 256, 0, stream>>>(gY, inv, out);
}